// Round 1
// baseline (82.232 us; speedup 1.0000x reference)
//
#include <hip/hip_runtime.h>
#include <math.h>

#define Bq 512
#define Dq 256

__device__ __forceinline__ float waveReduceSum(float v) {
    #pragma unroll
    for (int off = 32; off > 0; off >>= 1)
        v += __shfl_xor(v, off, 64);
    return v;
}

// Kernel 1: per-row L2 normalize, write transposed fT[k*Bq + i] and coef rows:
//   A1 = a, A2 = a^2, C1 = a*(1+a^3), C2 = (1+a^3)^2
__global__ __launch_bounds__(256) void prep_kernel(
        const float* __restrict__ feat,
        float* __restrict__ fT, float* __restrict__ C1, float* __restrict__ C2,
        float* __restrict__ A1, float* __restrict__ A2) {
    int i = blockIdx.x;
    int k = threadIdx.x;
    float x = feat[i * Dq + k];
    float ss = waveReduceSum(x * x);
    __shared__ float wsum[4];
    int wid = threadIdx.x >> 6, lane = threadIdx.x & 63;
    if (lane == 0) wsum[wid] = ss;
    __syncthreads();
    float tot = wsum[0] + wsum[1] + wsum[2] + wsum[3];
    float n = fmaxf(sqrtf(tot), 1e-12f);
    float a = x / n;
    float a2 = a * a;
    float a3 = a2 * a;
    float c0 = 1.0f + a3;
    fT[k * Bq + i] = a;
    A1[i * Dq + k] = a;
    A2[i * Dq + k] = a2;
    C1[i * Dq + k] = a * c0;
    C2[i * Dq + k] = c0 * c0;
}

// Kernel 2: block per i, thread per j. Computes S[i] = sum_j raw_s (incl diag),
// V[i] = sum_{j!=i} exp(raw_s) + 3*exp(raw_o).
__global__ __launch_bounds__(512) void pair_kernel(
        const float* __restrict__ fT,
        const float* __restrict__ C1, const float* __restrict__ C2,
        const float* __restrict__ A1, const float* __restrict__ A2,
        float* __restrict__ Sv, float* __restrict__ Vv) {
    int i = blockIdx.x;
    int j = threadIdx.x;
    const float* __restrict__ c1 = C1 + i * Dq;   // wave-uniform addresses -> s_load
    const float* __restrict__ c2 = C2 + i * Dq;
    const float* __restrict__ a1 = A1 + i * Dq;
    const float* __restrict__ a2p = A2 + i * Dq;

    float du = 0.f, nu = 0.f, dv = 0.f, nv = 0.f;
    #pragma unroll 8
    for (int k = 0; k < Dq; ++k) {
        float b  = fT[k * Bq + j];            // coalesced: lanes -> consecutive j
        float b2 = b * b;
        float w  = fmaf(a2p[k], b, 1.0f);     // w = 1 + a^2*b
        float wb = w * b;                     // v_k
        du = fmaf(c1[k], b,  du);
        nu = fmaf(c2[k], b2, nu);
        dv = fmaf(a1[k], wb, dv);
        nv = fmaf(wb,    wb, nv);
    }
    const float Tinv = 1.0f / 0.07f;
    float raw_s = du / fmaxf(sqrtf(nu), 1e-12f) * Tinv;
    float raw_o = dv / fmaxf(sqrtf(nv), 1e-12f) * Tinv;

    float sS = raw_s;                                       // diagonal included
    float sV = (j == i) ? 0.0f : (expf(raw_s) + 3.0f * expf(raw_o));

    sS = waveReduceSum(sS);
    sV = waveReduceSum(sV);
    __shared__ float redS[8], redV[8];
    int wid = threadIdx.x >> 6, lane = threadIdx.x & 63;
    if (lane == 0) { redS[wid] = sS; redV[wid] = sV; }
    __syncthreads();
    if (threadIdx.x == 0) {
        float S = 0.f, V = 0.f;
        #pragma unroll
        for (int w2 = 0; w2 < 8; ++w2) { S += redS[w2]; V += redV[w2]; }
        Sv[i] = S;
        Vv[i] = V;
    }
}

// Kernel 3: loss = -(1/B) * sum_i ( S[i]/B - log(V[i]) )
__global__ __launch_bounds__(512) void final_kernel(
        const float* __restrict__ Sv, const float* __restrict__ Vv,
        float* __restrict__ out) {
    int i = threadIdx.x;
    float t = Sv[i] * (1.0f / Bq) - logf(Vv[i]);
    t = waveReduceSum(t);
    __shared__ float red[8];
    int wid = i >> 6, lane = i & 63;
    if (lane == 0) red[wid] = t;
    __syncthreads();
    if (i == 0) {
        float s = 0.f;
        #pragma unroll
        for (int w = 0; w < 8; ++w) s += red[w];
        out[0] = -s / (float)Bq;
    }
}

extern "C" void kernel_launch(void* const* d_in, const int* in_sizes, int n_in,
                              void* d_out, int out_size, void* d_ws, size_t ws_size,
                              hipStream_t stream) {
    const float* feat = (const float*)d_in[0];
    float* ws = (float*)d_ws;
    float* fT = ws;                 // Dq*Bq
    float* C1 = fT + Bq * Dq;       // Bq*Dq
    float* C2 = C1 + Bq * Dq;
    float* A1 = C2 + Bq * Dq;
    float* A2 = A1 + Bq * Dq;
    float* Sv = A2 + Bq * Dq;       // Bq
    float* Vv = Sv + Bq;            // Bq

    prep_kernel<<<Bq, Dq, 0, stream>>>(feat, fT, C1, C2, A1, A2);
    pair_kernel<<<Bq, Bq, 0, stream>>>(fT, C1, C2, A1, A2, Sv, Vv);
    final_kernel<<<1, Bq, 0, stream>>>(Sv, Vv, (float*)d_out);
}

// Round 2
// 77.346 us; speedup vs baseline: 1.0632x; 1.0632x over previous
//
#include <hip/hip_runtime.h>
#include <math.h>

#define Bq 512
#define Dq 256

__device__ __forceinline__ float waveReduceSum(float v) {
    #pragma unroll
    for (int off = 32; off > 0; off >>= 1)
        v += __shfl_xor(v, off, 64);
    return v;
}

// Kernel 1: per-row L2 normalize, write transposed fT[k*Bq + i] and coef rows:
//   A1 = a, A2 = a^2, C1 = a*(1+a^3), C2 = (1+a^3)^2
__global__ __launch_bounds__(256) void prep_kernel(
        const float* __restrict__ feat,
        float* __restrict__ fT, float* __restrict__ C1, float* __restrict__ C2,
        float* __restrict__ A1, float* __restrict__ A2) {
    int i = blockIdx.x;
    int k = threadIdx.x;
    float x = feat[i * Dq + k];
    float ss = waveReduceSum(x * x);
    __shared__ float wsum[4];
    int wid = threadIdx.x >> 6, lane = threadIdx.x & 63;
    if (lane == 0) wsum[wid] = ss;
    __syncthreads();
    float tot = wsum[0] + wsum[1] + wsum[2] + wsum[3];
    float n = fmaxf(sqrtf(tot), 1e-12f);
    float a = x / n;
    float a2 = a * a;
    float a3 = a2 * a;
    float c0 = 1.0f + a3;
    fT[k * Bq + i] = a;
    A1[i * Dq + k] = a;
    A2[i * Dq + k] = a2;
    C1[i * Dq + k] = a * c0;
    C2[i * Dq + k] = c0 * c0;
}

// Kernel 2: block per i (256 threads), each thread owns j0=2t, j0+1.
// Coef rows staged in LDS (broadcast float4 reads); fT read as coalesced float2.
// S[i] = sum_j raw_s (incl diag), V[i] = sum_{j!=i} exp(raw_s) + 3*exp(raw_o).
__global__ __launch_bounds__(256) void pair_kernel(
        const float* __restrict__ fT,
        const float* __restrict__ C1, const float* __restrict__ C2,
        const float* __restrict__ A1, const float* __restrict__ A2,
        float* __restrict__ Sv, float* __restrict__ Vv) {
    const int i = blockIdx.x;
    const int t = threadIdx.x;
    const int j0 = 2 * t;

    __shared__ __align__(16) float s_c1[Dq];
    __shared__ __align__(16) float s_c2[Dq];
    __shared__ __align__(16) float s_a1[Dq];
    __shared__ __align__(16) float s_a2[Dq];
    s_c1[t] = C1[i * Dq + t];
    s_c2[t] = C2[i * Dq + t];
    s_a1[t] = A1[i * Dq + t];
    s_a2[t] = A2[i * Dq + t];
    __syncthreads();

    const float4* __restrict__ vc1 = (const float4*)s_c1;
    const float4* __restrict__ vc2 = (const float4*)s_c2;
    const float4* __restrict__ va1 = (const float4*)s_a1;
    const float4* __restrict__ va2 = (const float4*)s_a2;

    float du0 = 0.f, nu0 = 0.f, dv0 = 0.f, nv0 = 0.f;
    float du1 = 0.f, nu1 = 0.f, dv1 = 0.f, nv1 = 0.f;

    #pragma unroll 4
    for (int k4 = 0; k4 < Dq / 4; ++k4) {
        float4 c1 = vc1[k4];
        float4 c2 = vc2[k4];
        float4 a1 = va1[k4];
        float4 a2 = va2[k4];
        const float c1a[4] = {c1.x, c1.y, c1.z, c1.w};
        const float c2a[4] = {c2.x, c2.y, c2.z, c2.w};
        const float a1a[4] = {a1.x, a1.y, a1.z, a1.w};
        const float a2a[4] = {a2.x, a2.y, a2.z, a2.w};
        #pragma unroll
        for (int kk = 0; kk < 4; ++kk) {
            int k = k4 * 4 + kk;
            float2 b2v = *(const float2*)(fT + k * Bq + j0);  // coalesced 8B/lane
            // j0
            {
                float b = b2v.x;
                float bb = b * b;
                float w  = fmaf(a2a[kk], b, 1.0f);
                float wb = w * b;
                du0 = fmaf(c1a[kk], b,  du0);
                nu0 = fmaf(c2a[kk], bb, nu0);
                dv0 = fmaf(a1a[kk], wb, dv0);
                nv0 = fmaf(wb,      wb, nv0);
            }
            // j0+1
            {
                float b = b2v.y;
                float bb = b * b;
                float w  = fmaf(a2a[kk], b, 1.0f);
                float wb = w * b;
                du1 = fmaf(c1a[kk], b,  du1);
                nu1 = fmaf(c2a[kk], bb, nu1);
                dv1 = fmaf(a1a[kk], wb, dv1);
                nv1 = fmaf(wb,      wb, nv1);
            }
        }
    }

    const float Tinv = 1.0f / 0.07f;
    float raw_s0 = du0 / fmaxf(sqrtf(nu0), 1e-12f) * Tinv;
    float raw_o0 = dv0 / fmaxf(sqrtf(nv0), 1e-12f) * Tinv;
    float raw_s1 = du1 / fmaxf(sqrtf(nu1), 1e-12f) * Tinv;
    float raw_o1 = dv1 / fmaxf(sqrtf(nv1), 1e-12f) * Tinv;

    float sS = raw_s0 + raw_s1;   // diagonal included in S
    float sV = 0.f;
    if (j0 != i)     sV += expf(raw_s0) + 3.0f * expf(raw_o0);
    if (j0 + 1 != i) sV += expf(raw_s1) + 3.0f * expf(raw_o1);

    sS = waveReduceSum(sS);
    sV = waveReduceSum(sV);
    __shared__ float redS[4], redV[4];
    int wid = t >> 6, lane = t & 63;
    if (lane == 0) { redS[wid] = sS; redV[wid] = sV; }
    __syncthreads();
    if (t == 0) {
        float S = 0.f, V = 0.f;
        #pragma unroll
        for (int w2 = 0; w2 < 4; ++w2) { S += redS[w2]; V += redV[w2]; }
        Sv[i] = S;
        Vv[i] = V;
    }
}

// Kernel 3: loss = -(1/B) * sum_i ( S[i]/B - log(V[i]) )
__global__ __launch_bounds__(512) void final_kernel(
        const float* __restrict__ Sv, const float* __restrict__ Vv,
        float* __restrict__ out) {
    int i = threadIdx.x;
    float t = Sv[i] * (1.0f / Bq) - logf(Vv[i]);
    t = waveReduceSum(t);
    __shared__ float red[8];
    int wid = i >> 6, lane = i & 63;
    if (lane == 0) red[wid] = t;
    __syncthreads();
    if (i == 0) {
        float s = 0.f;
        #pragma unroll
        for (int w = 0; w < 8; ++w) s += red[w];
        out[0] = -s / (float)Bq;
    }
}

extern "C" void kernel_launch(void* const* d_in, const int* in_sizes, int n_in,
                              void* d_out, int out_size, void* d_ws, size_t ws_size,
                              hipStream_t stream) {
    const float* feat = (const float*)d_in[0];
    float* ws = (float*)d_ws;
    float* fT = ws;                 // Dq*Bq
    float* C1 = fT + Bq * Dq;       // Bq*Dq
    float* C2 = C1 + Bq * Dq;
    float* A1 = C2 + Bq * Dq;
    float* A2 = A1 + Bq * Dq;
    float* Sv = A2 + Bq * Dq;       // Bq
    float* Vv = Sv + Bq;            // Bq

    prep_kernel<<<Bq, Dq, 0, stream>>>(feat, fT, C1, C2, A1, A2);
    pair_kernel<<<Bq, 256, 0, stream>>>(fT, C1, C2, A1, A2, Sv, Vv);
    final_kernel<<<1, Bq, 0, stream>>>(Sv, Vv, (float*)d_out);
}